// Round 18
// baseline (252.938 us; speedup 1.0000x reference)
//
#include <hip/hip_runtime.h>
#include <hip/hip_bf16.h>

typedef short short8 __attribute__((ext_vector_type(8)));
typedef short short4v __attribute__((ext_vector_type(4)));
typedef unsigned short ushort8v __attribute__((ext_vector_type(8)));
typedef unsigned short ushort4v __attribute__((ext_vector_type(4)));
typedef float f32x4 __attribute__((ext_vector_type(4)));
typedef unsigned int uint32;

#define USH unsigned short

__device__ __forceinline__ USH f2bf(float f) {
  unsigned int u = __builtin_bit_cast(unsigned int, f);
  u = (u + 0x7FFFu + ((u >> 16) & 1u)) >> 16;
  return (USH)u;
}

// packed RNE f32x2 -> bf16x2 via official HIP intrinsic (verified r9/r12/r13/r15)
__device__ __forceinline__ uint32 pkbf2(float lo, float hi) {
  __hip_bfloat162 h2 = __float22bfloat162_rn(float2{lo, hi});
  uint32 r;
  __builtin_memcpy(&r, &h2, 4);
  return r;
}

__device__ __forceinline__ f32x4 mfma16(short8 a, short8 b, f32x4 c) {
  return __builtin_amdgcn_mfma_f32_16x16x32_bf16(a, b, c, 0, 0, 0);
}

// 16x16x16 bf16 MFMA (legacy K=16 shape; A/B = 4 bf16/lane at k = (lane>>4)*4+e)
__device__ __forceinline__ f32x4 mfma16h(short4v a, short4v b, f32x4 c) {
#if __has_builtin(__builtin_amdgcn_mfma_f32_16x16x16bf16_1k)
  return __builtin_amdgcn_mfma_f32_16x16x16bf16_1k(a, b, c, 0, 0, 0);
#else
  f32x4 d;
  asm volatile("v_mfma_f32_16x16x16_bf16 %0, %1, %2, %3"
               : "=&v"(d)
               : "v"(a), "v"(b), "v"(c));
  return d;
#endif
}

// async global->LDS, 16B per lane, dest = base + lane*16 (linear)
__device__ __forceinline__ void gload16(const USH* g, USH* l) {
  __builtin_amdgcn_global_load_lds(
      (const __attribute__((address_space(1))) unsigned int*)g,
      (__attribute__((address_space(3))) unsigned int*)l, 16, 0, 0);
}

__device__ __forceinline__ f32x4 vmax4(f32x4 a, f32x4 b) {
  f32x4 r;
  r[0] = fmaxf(a[0], b[0]);
  r[1] = fmaxf(a[1], b[1]);
  r[2] = fmaxf(a[2], b[2]);
  r[3] = fmaxf(a[3], b[3]);
  return r;
}

union Frag4 {
  uint32 u[2];
  short4v s4;
};

// ---------------- fp32 -> bf16 convert ----------------
__global__ __launch_bounds__(256) void cvt_bf16(const float* __restrict__ in,
                                                USH* __restrict__ out, int n4) {
  int i = blockIdx.x * 256 + threadIdx.x;
  if (i >= n4) return;
  f32x4 v = *(const f32x4*)(in + (size_t)i * 4);
  ushort4v o;
#pragma unroll
  for (int k = 0; k < 4; k++) o[k] = f2bf(v[k]);
  *(ushort4v*)(out + (size_t)i * 4) = o;
}

// ---------------- GEMM: C[M,N] = A[M,K] @ B[N,K]^T + bias ----------------
template <bool OUT_F32>
__global__ __launch_bounds__(256) void gemm_bt(const USH* __restrict__ A,
                                               const USH* __restrict__ B,
                                               const float* __restrict__ bias,
                                               void* __restrict__ Cout,
                                               int M, int N, int K) {
  __shared__ __align__(16) USH As[128 * 64];
  __shared__ __align__(16) USH Bs[128 * 64];
  const int tid = threadIdx.x;
  const int row0 = blockIdx.x * 128;
  const int col0 = blockIdx.y * 128;
  const int wid = tid >> 6, lane = tid & 63;
  const int wr = (wid >> 1) * 64, wc = (wid & 1) * 64;
  const int lmod = lane & 15, ldiv = lane >> 4;
  const int asw = lmod & 7;
  const int srow = lane >> 3;
  const int scol = ((lane & 7) ^ srow) * 8;

  f32x4 acc[4][4];
#pragma unroll
  for (int i = 0; i < 4; i++)
#pragma unroll
    for (int j = 0; j < 4; j++) acc[i][j] = (f32x4){0.f, 0.f, 0.f, 0.f};

  const USH* Ab = A + (size_t)row0 * K;
  const USH* Bb = B + (size_t)col0 * K;

  for (int k0 = 0; k0 < K; k0 += 64) {
    __syncthreads();
#pragma unroll
    for (int i = 0; i < 4; i++) {
      int r0 = wid * 32 + i * 8;
      int r = r0 + srow;
      gload16(&Ab[(size_t)r * K + k0 + scol], &As[r0 * 64]);
      gload16(&Bb[(size_t)r * K + k0 + scol], &Bs[r0 * 64]);
    }
    __syncthreads();
#pragma unroll
    for (int kk = 0; kk < 64; kk += 32) {
      short8 a[4], b[4];
#pragma unroll
      for (int i = 0; i < 4; i++)
        a[i] = *(const short8*)&As[(wr + i * 16 + lmod) * 64 +
                                   ((((kk >> 3) + ldiv) ^ asw) << 3)];
#pragma unroll
      for (int i = 0; i < 4; i++)
        b[i] = *(const short8*)&Bs[(wc + i * 16 + lmod) * 64 +
                                   ((((kk >> 3) + ldiv) ^ asw) << 3)];
#pragma unroll
      for (int i = 0; i < 4; i++)
#pragma unroll
        for (int j = 0; j < 4; j++)
          acc[i][j] = mfma16(a[i], b[j], acc[i][j]);
    }
  }

  const int r4 = ldiv * 4;
#pragma unroll
  for (int i = 0; i < 4; i++) {
#pragma unroll
    for (int j = 0; j < 4; j++) {
      int rr = row0 + wr + i * 16 + r4;
      int cc = col0 + wc + j * 16 + lmod;
      float bv = bias[cc];
#pragma unroll
      for (int t = 0; t < 4; t++) {
        float v = acc[i][j][t] + bv;
        if (OUT_F32)
          ((float*)Cout)[(size_t)(rr + t) * N + cc] = v;
        else
          ((USH*)Cout)[(size_t)(rr + t) * N + cc] = f2bf(v);
      }
    }
  }
}

// ---------------- V transpose ----------------
__global__ __launch_bounds__(256) void vtrans(const USH* __restrict__ qkv,
                                              USH* __restrict__ vT) {
  __shared__ __align__(16) USH t[64][72];
  const int bh = blockIdx.y, b = bh >> 3, h = bh & 7;
  const int s0 = blockIdx.x * 64;
  const int tid = threadIdx.x;
  const int r = tid >> 4, c4 = (tid & 15) * 4;
#pragma unroll
  for (int i = 0; i < 4; i++) {
    int row = r + i * 16;
    *(ushort4v*)&t[row][c4] =
        *(const ushort4v*)&qkv[(size_t)(b * 4096 + s0 + row) * 1536 + 1024 + h * 64 + c4];
  }
  __syncthreads();
  const int d = tid >> 2, sb = (tid & 3) * 16;
  size_t ob = (size_t)(bh * 64 + d) * 4096 + s0 + sb;
#pragma unroll
  for (int half = 0; half < 2; half++) {
    ushort8v o;
#pragma unroll
    for (int k = 0; k < 8; k++) o[k] = t[sb + half * 8 + k][d];
    *(ushort8v*)&vT[ob + half * 8] = o;
  }
}

// ---------------- Flash attention v18: r17 math, unroll-2 static buffers ----------------

struct AttnState {
  short8 qf00, qf01, qf10, qf11;
  f32x4 acc0[4], acc1[4];
  f32x4 l0, l1;
  float nmk0, nmk1;
  int lmod, ldiv, ksw;
};

template <bool FIRST>
__device__ __forceinline__ void attn_body(const USH* __restrict__ Kc,
                                          const USH* __restrict__ Vc,
                                          AttnState& st) {
  const int lmod = st.lmod, ldiv = st.ldiv, ksw = st.ksw;
  const float K2 = 0.18033688011112042f;  // log2(e)/8
  const f32x4 z4 = (f32x4){0.f, 0.f, 0.f, 0.f};

  // ---- QK^T swapped: s{0,1}[n][j] -> q = lmod, kv = n*16 + ldiv*4 + j ----
  f32x4 s0[4], s1[4];
  __builtin_amdgcn_s_setprio(1);
#pragma unroll
  for (int n = 0; n < 4; n++) {
    const USH* kr = Kc + (n * 16 + lmod) * 64;
    short8 kf0 = *(const short8*)(kr + ((ldiv ^ ksw) << 3));
    short8 kf1 = *(const short8*)(kr + (((4 + ldiv) ^ ksw) << 3));
    s0[n] = mfma16(kf0, st.qf00, z4);
    s0[n] = mfma16(kf1, st.qf01, s0[n]);
    s1[n] = mfma16(kf0, st.qf10, z4);
    s1[n] = mfma16(kf1, st.qf11, s1[n]);
  }
  __builtin_amdgcn_s_setprio(0);

  // ---- m fixed at tile 0 (full row-max); exact (m-invariant math, r17) ----
  if (FIRST) {
    f32x4 u0 = vmax4(vmax4(s0[0], s0[1]), vmax4(s0[2], s0[3]));
    float p0 = fmaxf(fmaxf(u0[0], u0[1]), fmaxf(u0[2], u0[3]));
    p0 = fmaxf(p0, __shfl_xor(p0, 16));
    p0 = fmaxf(p0, __shfl_xor(p0, 32));
    f32x4 u1 = vmax4(vmax4(s1[0], s1[1]), vmax4(s1[2], s1[3]));
    float p1 = fmaxf(fmaxf(u1[0], u1[1]), fmaxf(u1[2], u1[3]));
    p1 = fmaxf(p1, __shfl_xor(p1, 16));
    p1 = fmaxf(p1, __shfl_xor(p1, 32));
    st.nmk0 = -p0 * K2;
    st.nmk1 = -p1 * K2;
  }
  const float nmk0 = st.nmk0, nmk1 = st.nmk1;

  // ---- P in-register -> 16x16x16 PV (+ rowsum); V shared by both groups ----
  short4v ones4;
#pragma unroll
  for (int i = 0; i < 4; i++) ones4[i] = (short)0x3F80;
#pragma unroll
  for (int n = 0; n < 4; n++) {
    Frag4 pa0, pa1;
    {
      float e0 = __builtin_amdgcn_exp2f(fmaf(s0[n][0], K2, nmk0));
      float e1 = __builtin_amdgcn_exp2f(fmaf(s0[n][1], K2, nmk0));
      float e2 = __builtin_amdgcn_exp2f(fmaf(s0[n][2], K2, nmk0));
      float e3 = __builtin_amdgcn_exp2f(fmaf(s0[n][3], K2, nmk0));
      pa0.u[0] = pkbf2(e0, e1);
      pa0.u[1] = pkbf2(e2, e3);
    }
    {
      float e0 = __builtin_amdgcn_exp2f(fmaf(s1[n][0], K2, nmk1));
      float e1 = __builtin_amdgcn_exp2f(fmaf(s1[n][1], K2, nmk1));
      float e2 = __builtin_amdgcn_exp2f(fmaf(s1[n][2], K2, nmk1));
      float e3 = __builtin_amdgcn_exp2f(fmaf(s1[n][3], K2, nmk1));
      pa1.u[0] = pkbf2(e0, e1);
      pa1.u[1] = pkbf2(e2, e3);
    }
    __builtin_amdgcn_s_setprio(1);
    st.l0 = mfma16h(pa0.s4, ones4, st.l0);
    st.l1 = mfma16h(pa1.s4, ones4, st.l1);
#pragma unroll
    for (int n2 = 0; n2 < 4; n2++) {
      // V read: stored c4' = c4 ^ (row&14), row = n2*16+lmod, c4 = n*4+ldiv
      const int vcol = (((n * 4 + ldiv) ^ (lmod & 14)) << 2);
      short4v vf = *(const short4v*)(Vc + (n2 * 16 + lmod) * 64 + vcol);
      st.acc0[n2] = mfma16h(pa0.s4, vf, st.acc0[n2]);
      st.acc1[n2] = mfma16h(pa1.s4, vf, st.acc1[n2]);
    }
    __builtin_amdgcn_s_setprio(0);
  }
}

__global__ __launch_bounds__(256, 4) void attn_fwd(const USH* __restrict__ qkv,
                                                   const USH* __restrict__ vT,
                                                   USH* __restrict__ attno) {
  __shared__ __align__(16) USH Ks[2][64 * 64];  // 16 KB
  __shared__ __align__(16) USH Vs[2][64 * 64];  // 16 KB

  const int fb = blockIdx.x;
  const int b3 = fb & 7;
  const int rest = fb >> 3;
  const int qb = rest & 31;
  const int bh = b3 + 8 * (rest >> 5);
  const int b = bh >> 3, h = bh & 7;

  const int wid = threadIdx.x >> 6, lane = threadIdx.x & 63;
  const int lmod = lane & 15, ldiv = lane >> 4;
  const int qrow0 = qb * 128 + wid * 32;

  AttnState st;
  st.lmod = lmod;
  st.ldiv = ldiv;
  st.ksw = lmod & 7;
  {
    const USH* qp = qkv + (size_t)(b * 4096 + qrow0 + lmod) * 1536 + h * 64 + ldiv * 8;
    st.qf00 = *(const short8*)qp;
    st.qf01 = *(const short8*)(qp + 32);
    qp += (size_t)16 * 1536;
    st.qf10 = *(const short8*)qp;
    st.qf11 = *(const short8*)(qp + 32);
  }
#pragma unroll
  for (int n = 0; n < 4; n++) {
    st.acc0[n] = (f32x4){0.f, 0.f, 0.f, 0.f};
    st.acc1[n] = (f32x4){0.f, 0.f, 0.f, 0.f};
  }
  st.l0 = (f32x4){0.f, 0.f, 0.f, 0.f};
  st.l1 = st.l0;
  st.nmk0 = 0.f;
  st.nmk1 = 0.f;

  const USH* kbase = qkv + (size_t)b * 4096 * 1536 + 512 + h * 64;
  const USH* vbase = vT + (size_t)bh * 64 * 4096;
  const int srow = lane >> 3;
  const int scol = ((lane & 7) ^ srow) * 8;

  // running global staging pointers (advance 64 kv per stage)
  const int ra = wid * 16 + srow;      // i=0 row in tile
  const int rb = wid * 16 + 8 + srow;  // i=1
  const USH* kga = kbase + (size_t)ra * 1536 + scol;
  const USH* kgb = kbase + (size_t)rb * 1536 + scol;
  const USH* vga = vbase + (size_t)ra * 4096 + ((2 * (lane & 7)) ^ (ra & 14)) * 4;
  const USH* vgb = vbase + (size_t)rb * 4096 + ((2 * (lane & 7)) ^ (rb & 14)) * 4;

#define STAGE(BU)                                   \
  do {                                              \
    gload16(kga, &Ks[BU][(wid * 16) * 64]);         \
    gload16(kgb, &Ks[BU][(wid * 16 + 8) * 64]);     \
    gload16(vga, &Vs[BU][(wid * 16) * 64]);         \
    gload16(vgb, &Vs[BU][(wid * 16 + 8) * 64]);     \
    kga += 64 * 1536;                               \
    kgb += 64 * 1536;                               \
    vga += 64;                                      \
    vgb += 64;                                      \
  } while (0)

  STAGE(0);  // tile 0 -> buf0

  // t = 0 (peeled; computes nmk)
  __syncthreads();
  STAGE(1);  // tile 1 -> buf1
  attn_body<true>(&Ks[0][0], &Vs[0][0], st);

  // t = 1..62 as 31 unrolled pairs (odd: buf1, even: buf0)
#pragma unroll 1
  for (int tt = 0; tt < 31; ++tt) {
    __syncthreads();
    STAGE(0);  // tile 2tt+2 -> buf0
    attn_body<false>(&Ks[1][0], &Vs[1][0], st);
    __syncthreads();
    STAGE(1);  // tile 2tt+3 -> buf1
    attn_body<false>(&Ks[0][0], &Vs[0][0], st);
  }

  // t = 63 (buf1, no further stage)
  __syncthreads();
  attn_body<false>(&Ks[1][0], &Vs[1][0], st);
#undef STAGE

  // ---- epilogue (acc layout: q = ldiv*4+j, dh = n*16+lmod) ----
  float iv0[4], iv1[4];
#pragma unroll
  for (int j = 0; j < 4; j++) {
    iv0[j] = 1.0f / st.l0[j];
    iv1[j] = 1.0f / st.l1[j];
  }
  USH* ob = attno + (size_t)(b * 4096 + qrow0) * 512 + h * 64;
#pragma unroll
  for (int n = 0; n < 4; n++) {
#pragma unroll
    for (int j = 0; j < 4; j++) {
      ob[(size_t)(ldiv * 4 + j) * 512 + n * 16 + lmod] = f2bf(st.acc0[n][j] * iv0[j]);
      ob[(size_t)(16 + ldiv * 4 + j) * 512 + n * 16 + lmod] = f2bf(st.acc1[n][j] * iv1[j]);
    }
  }
}

// ---------------- launch ----------------
extern "C" void kernel_launch(void* const* d_in, const int* in_sizes, int n_in,
                              void* d_out, int out_size, void* d_ws, size_t ws_size,
                              hipStream_t stream) {
  const float* x = (const float*)d_in[0];      // (4,4096,512)
  const float* w_in = (const float*)d_in[1];   // (1536,512)
  const float* b_in = (const float*)d_in[2];   // (1536)
  const float* w_out = (const float*)d_in[3];  // (512,512)
  const float* b_out = (const float*)d_in[4];  // (512)
  float* out = (float*)d_out;                  // (4,4096,512) fp32

  char* ws = (char*)d_ws;
  USH* xb = (USH*)(ws);                        // 16 MB (reused as attno later)
  USH* winb = (USH*)(ws + 16777216);           // 1.5 MB
  USH* woutb = (USH*)(ws + 18350080);          // 0.5 MB
  USH* qkv = (USH*)(ws + 18874368);            // 48 MB
  USH* vT = (USH*)(ws + 69206016);             // 16 MB
  USH* attno = xb;                             // alias: xb dead after gemm1

  cvt_bf16<<<8192, 256, 0, stream>>>(x, xb, 2097152);
  cvt_bf16<<<768, 256, 0, stream>>>(w_in, winb, 196608);
  cvt_bf16<<<256, 256, 0, stream>>>(w_out, woutb, 65536);

  gemm_bt<false><<<dim3(128, 12), 256, 0, stream>>>(xb, winb, b_in, qkv, 16384, 1536, 512);
  vtrans<<<dim3(64, 32), 256, 0, stream>>>(qkv, vT);
  attn_fwd<<<1024, 256, 0, stream>>>(qkv, vT, attno);
  gemm_bt<true><<<dim3(128, 4), 256, 0, stream>>>(attno, woutb, b_out, out, 16384, 512, 512);
}